// Round 1
// baseline (295.883 us; speedup 1.0000x reference)
//
#include <hip/hip_runtime.h>
#include <hip/hip_bf16.h>
#include <math.h>

#define TID ((int)threadIdx.x)

typedef float f32x4 __attribute__((ext_vector_type(4)));
typedef short s16x8 __attribute__((ext_vector_type(8)));

__device__ __forceinline__ unsigned short f2bf(float f) {
  union { float f; unsigned u; } v; v.f = f;
  unsigned r = v.u + 0x7FFFu + ((v.u >> 16) & 1u);
  return (unsigned short)(r >> 16);
}
__device__ __forceinline__ float bf2f(unsigned short h) {
  union { unsigned u; float f; } v; v.u = ((unsigned)h) << 16;
  return v.f;
}

// ---------------- prep: weight transpose->bf16 + RoPE trig table ----------------
// wt layout: m in {eeg,k,v}: wt[m*65536 + col*256 + k]  (WT[N][K], k contiguous)
// trig layout: trig[n*16 + p] = (cos(n*inv_p), sin(n*inv_p)), inv_p = 10000^(-p/16)
__global__ void prep_kernel(const float* __restrict__ eeg_w,
                            const float* __restrict__ k_w,
                            const float* __restrict__ v_w,
                            unsigned short* __restrict__ wt,
                            float2* __restrict__ trig) {
  int gid = blockIdx.x * 256 + TID;            // grid = 1024*256 = 262144 exactly
  if (gid < 3 * 65536) {
    int m = gid >> 16, e = gid & 65535;
    int i = e >> 8, j = e & 255;               // read W[i][j] coalesced over j
    const float* W = (m == 0) ? eeg_w : ((m == 1) ? k_w : v_w);
    wt[m * 65536 + j * 256 + i] = f2bf(W[i * 256 + j]);
  } else {
    int e = gid - 3 * 65536;                   // < 65536
    int n = e >> 4, p = e & 15;
    float inv = exp2f(-(float)p * 0.8304820237218406f);  // 10000^(-p/16)
    float a = (float)n * inv;
    trig[e] = make_float2(cosf(a), sinf(a));
  }
}

// ---------------- query path: proj -> LN (output) -> Q proj -> RoPE -> l2norm ----------------
__global__ __launch_bounds__(256) void q_kernel(
    const float* __restrict__ stim_feat, const float* __restrict__ temp_feat,
    const float* __restrict__ stim_w, const float* __restrict__ stim_b,
    const float* __restrict__ temp_w, const float* __restrict__ temp_b,
    const float* __restrict__ q_w, const float* __restrict__ q_b,
    const float* __restrict__ lnq_g, const float* __restrict__ lnq_b,
    float* __restrict__ out_query, float* __restrict__ qhat) {
  int b = blockIdx.x >> 1, q = blockIdx.x & 1;
  __shared__ float f[256];
  __shared__ float red[8];
  const float* feat = (q ? temp_feat : stim_feat) + b * 256;
  const float* W = q ? temp_w : stim_w;
  const float* bias = q ? temp_b : stim_b;
  f[TID] = feat[TID];
  __syncthreads();
  float acc = bias[TID];
#pragma unroll 8
  for (int i = 0; i < 256; ++i) acc = fmaf(f[i], W[i * 256 + TID], acc);
  // block LN over 256
  float s1 = acc, s2 = acc * acc;
#pragma unroll
  for (int m = 1; m < 64; m <<= 1) { s1 += __shfl_xor(s1, m, 64); s2 += __shfl_xor(s2, m, 64); }
  if ((TID & 63) == 0) { red[TID >> 6] = s1; red[4 + (TID >> 6)] = s2; }
  __syncthreads();
  s1 = red[0] + red[1] + red[2] + red[3];
  s2 = red[4] + red[5] + red[6] + red[7];
  float mean = s1 * (1.f / 256.f);
  float var = s2 * (1.f / 256.f) - mean * mean;
  float rstd = rsqrtf(var + 1e-5f);
  float qln = (acc - mean) * rstd * lnq_g[TID] + lnq_b[TID];
  out_query[(b * 2 + q) * 256 + TID] = qln;
  __syncthreads();
  f[TID] = qln;
  __syncthreads();
  float a2 = q_b[TID];
#pragma unroll 8
  for (int i = 0; i < 256; ++i) a2 = fmaf(f[i], q_w[i * 256 + TID], a2);
  __syncthreads();
  f[TID] = a2;
  __syncthreads();
  float partner = f[TID ^ 1];
  int p = (TID >> 1) & 15;
  float inv = exp2f(-(float)p * 0.8304820237218406f);
  float ang = (float)q * inv;
  float cc_ = cosf(ang), ss_ = sinf(ang);
  float r = (TID & 1) ? fmaf(a2, cc_, partner * ss_) : fmaf(a2, cc_, -partner * ss_);
  float sq = r * r;
#pragma unroll
  for (int m = 1; m < 32; m <<= 1) sq += __shfl_xor(sq, m, 32);   // per-head (32 lanes)
  float rs = 1.f / fmaxf(sqrtf(sq), 1e-12f);
  qhat[(b * 2 + q) * 256 + TID] = r * rs;
}

// ---------------- main: eeg proj -> LN -> {K proj -> RoPE/l2norm/scores, V proj -> ws} ----------------
__global__ __launch_bounds__(256) void main_kernel(
    const float* __restrict__ x,
    const float* __restrict__ eeg_b,
    const float* __restrict__ k_b,
    const float* __restrict__ v_b,
    const float* __restrict__ lnk_g,
    const float* __restrict__ lnk_b,
    const unsigned short* __restrict__ wt_eeg,
    const unsigned short* __restrict__ wt_k,
    const unsigned short* __restrict__ wt_v,
    const float2* __restrict__ trig,
    const float* __restrict__ qhat,
    float* __restrict__ scores,
    unsigned short* __restrict__ vws) {

  __shared__ __align__(16) unsigned short A[64 * 256];  // 32KB, XOR-swizzled bf16 tile
  __shared__ float2 TR[64 * 16];                        // 8KB trig rows for this tile
  __shared__ float PS[64 * 8];                          // LN partials [row][wave*2+{s,ss}]
  __shared__ float2 ST[64];                             // (mean, rstd) per row

  const int tid = TID;
  const int w = tid >> 6, l = tid & 63, g = l >> 4, c = l & 15;
  const int r0 = blockIdx.x * 64;
  const int b = r0 >> 12;
  const int n0 = r0 & 4095;

  // ---- stage X (fp32 -> bf16, swizzled) + trig rows ----
#pragma unroll
  for (int i = 0; i < 8; ++i) {
    int ch = i * 256 + tid;
    int row = ch >> 5, cc = ch & 31;
    const float4* gp = (const float4*)(x + (size_t)(r0 + row) * 256 + cc * 8);
    float4 u0 = gp[0], u1 = gp[1];
    s16x8 pk;
    pk[0] = (short)f2bf(u0.x); pk[1] = (short)f2bf(u0.y);
    pk[2] = (short)f2bf(u0.z); pk[3] = (short)f2bf(u0.w);
    pk[4] = (short)f2bf(u1.x); pk[5] = (short)f2bf(u1.y);
    pk[6] = (short)f2bf(u1.z); pk[7] = (short)f2bf(u1.w);
    *(s16x8*)&A[row * 256 + ((cc ^ (row & 7)) * 8)] = pk;
  }
#pragma unroll
  for (int i = 0; i < 4; ++i) {
    int e = i * 256 + tid;  // < 1024
    int rr = e >> 4, pp = e & 15;
    TR[e] = trig[(size_t)(n0 + rr) * 16 + pp];
  }
  __syncthreads();

  f32x4 acc[4][4];

#define DO_GEMM(WT) do {                                                          \
    _Pragma("unroll") for (int rb = 0; rb < 4; ++rb)                              \
      _Pragma("unroll") for (int cb = 0; cb < 4; ++cb)                            \
        acc[rb][cb] = (f32x4){0.f, 0.f, 0.f, 0.f};                                \
    _Pragma("unroll") for (int ks = 0; ks < 8; ++ks) {                            \
      s16x8 af[4]; s16x8 bfr[4];                                                  \
      _Pragma("unroll") for (int rb = 0; rb < 4; ++rb) {                          \
        int row = rb * 16 + c; int kc = ks * 4 + g;                               \
        af[rb] = *(const s16x8*)&A[row * 256 + ((kc ^ (row & 7)) * 8)];           \
      }                                                                           \
      _Pragma("unroll") for (int cb = 0; cb < 4; ++cb) {                          \
        int col = w * 64 + cb * 16 + c;                                           \
        bfr[cb] = *(const s16x8*)&(WT)[col * 256 + ks * 32 + g * 8];              \
      }                                                                           \
      _Pragma("unroll") for (int rb = 0; rb < 4; ++rb)                            \
        _Pragma("unroll") for (int cb = 0; cb < 4; ++cb)                          \
          acc[rb][cb] = __builtin_amdgcn_mfma_f32_16x16x32_bf16(                  \
              af[rb], bfr[cb], acc[rb][cb], 0, 0, 0);                             \
    } } while (0)

  // per-lane column constants
  float ebias[4], kbias[4], vbias[4], gg[4], bb[4], qh0[4], qh1[4];
  int cols[4];
#pragma unroll
  for (int cb = 0; cb < 4; ++cb) {
    int col = w * 64 + cb * 16 + c;
    cols[cb] = col;
    ebias[cb] = eeg_b[col]; kbias[cb] = k_b[col]; vbias[cb] = v_b[col];
    gg[cb] = lnk_g[col]; bb[cb] = lnk_b[col];
    qh0[cb] = qhat[(b * 2 + 0) * 256 + col];
    qh1[cb] = qhat[(b * 2 + 1) * 256 + col];
  }

  // ---- GEMM1: eeg projection ----
  DO_GEMM(wt_eeg);

  // ---- LN stats from accumulators ----
  {
    float ps[4][4], pq[4][4];
#pragma unroll
    for (int rb = 0; rb < 4; ++rb)
#pragma unroll
      for (int r = 0; r < 4; ++r) {
        float s = 0.f, q2 = 0.f;
#pragma unroll
        for (int cb = 0; cb < 4; ++cb) {
          float v = acc[rb][cb][r] + ebias[cb];
          s += v; q2 += v * v;
        }
        ps[rb][r] = s; pq[rb][r] = q2;
      }
#pragma unroll
    for (int m = 1; m < 16; m <<= 1)
#pragma unroll
      for (int rb = 0; rb < 4; ++rb)
#pragma unroll
        for (int r = 0; r < 4; ++r) {
          ps[rb][r] += __shfl_xor(ps[rb][r], m, 64);
          pq[rb][r] += __shfl_xor(pq[rb][r], m, 64);
        }
    // lane c writes (rb,r) = (c>>2, c&3): static-index select (rule #20)
    float outS = 0.f, outQ = 0.f;
#pragma unroll
    for (int rb = 0; rb < 4; ++rb)
#pragma unroll
      for (int r = 0; r < 4; ++r)
        if (c == rb * 4 + r) { outS = ps[rb][r]; outQ = pq[rb][r]; }
    int row = (c >> 2) * 16 + g * 4 + (c & 3);
    PS[row * 8 + w * 2 + 0] = outS;
    PS[row * 8 + w * 2 + 1] = outQ;
  }
  __syncthreads();
  if (tid < 64) {
    float s = PS[tid * 8 + 0] + PS[tid * 8 + 2] + PS[tid * 8 + 4] + PS[tid * 8 + 6];
    float q2 = PS[tid * 8 + 1] + PS[tid * 8 + 3] + PS[tid * 8 + 5] + PS[tid * 8 + 7];
    float mean = s * (1.f / 256.f);
    float var = q2 * (1.f / 256.f) - mean * mean;
    ST[tid] = make_float2(mean, rsqrtf(var + 1e-5f));
  }
  __syncthreads();

  // ---- LN -> bf16 back into region A (all GEMM1 reads completed at barrier) ----
#pragma unroll
  for (int rb = 0; rb < 4; ++rb)
#pragma unroll
    for (int r = 0; r < 4; ++r) {
      int row = rb * 16 + g * 4 + r;
      float2 st = ST[row];
#pragma unroll
      for (int cb = 0; cb < 4; ++cb) {
        float v = (acc[rb][cb][r] + ebias[cb] - st.x) * st.y * gg[cb] + bb[cb];
        A[row * 256 + (cols[cb] ^ ((row & 7) * 8))] = f2bf(v);
      }
    }
  __syncthreads();

  // ---- GEMM2: K projection; epilogue: RoPE -> l2norm -> scores ----
  DO_GEMM(wt_k);
#pragma unroll
  for (int rb = 0; rb < 4; ++rb) {
    float rot[4][4];   // [cb][r]
    float ssq[2][4];   // [hh][r]
#pragma unroll
    for (int hh = 0; hh < 2; ++hh)
#pragma unroll
      for (int r = 0; r < 4; ++r) ssq[hh][r] = 0.f;
#pragma unroll
    for (int cb = 0; cb < 4; ++cb) {
      int pp = (cols[cb] >> 1) & 15;
#pragma unroll
      for (int r = 0; r < 4; ++r) {
        int row = rb * 16 + g * 4 + r;
        float v = acc[rb][cb][r] + kbias[cb];
        float pv = __shfl_xor(v, 1, 64);           // partner column (col^1)
        float2 cs2 = TR[row * 16 + pp];
        float rv = (c & 1) ? fmaf(v, cs2.x, pv * cs2.y)
                           : fmaf(v, cs2.x, -pv * cs2.y);
        rot[cb][r] = rv;
        ssq[cb >> 1][r] += rv * rv;
      }
    }
#pragma unroll
    for (int m = 1; m < 16; m <<= 1)
#pragma unroll
      for (int hh = 0; hh < 2; ++hh)
#pragma unroll
        for (int r = 0; r < 4; ++r) ssq[hh][r] += __shfl_xor(ssq[hh][r], m, 64);
    float sc[2][4][2];  // [hh][r][q]
#pragma unroll
    for (int hh = 0; hh < 2; ++hh)
#pragma unroll
      for (int r = 0; r < 4; ++r) {
        float is = 1.f / fmaxf(sqrtf(ssq[hh][r]), 1e-12f);
        float s0 = 0.f, s1 = 0.f;
#pragma unroll
        for (int j = 0; j < 2; ++j) {
          int cb = hh * 2 + j;
          float kh = rot[cb][r] * is;
          s0 = fmaf(kh, qh0[cb], s0);
          s1 = fmaf(kh, qh1[cb], s1);
        }
        sc[hh][r][0] = s0; sc[hh][r][1] = s1;
      }
#pragma unroll
    for (int m = 1; m < 16; m <<= 1)
#pragma unroll
      for (int hh = 0; hh < 2; ++hh)
#pragma unroll
        for (int r = 0; r < 4; ++r)
#pragma unroll
          for (int q = 0; q < 2; ++q) sc[hh][r][q] += __shfl_xor(sc[hh][r][q], m, 64);
    // each of the 16 lanes in a group writes one (hh,r,q)
    int qi = c & 1, ri = (c >> 1) & 3, hi = c >> 3;
    float val = 0.f;
#pragma unroll
    for (int hh = 0; hh < 2; ++hh)
#pragma unroll
      for (int r = 0; r < 4; ++r)
#pragma unroll
        for (int q = 0; q < 2; ++q)
          if (hh == hi && r == ri && q == qi) val = sc[hh][r][q];
    int row = rb * 16 + g * 4 + ri;
    int h = w * 2 + hi;
    scores[(size_t)((b * 8 + h) * 2 + qi) * 4096 + n0 + row] = val * 0.17677669529663687f;
  }

  // ---- GEMM3: V projection; stage to LDS then coalesced global write ----
  DO_GEMM(wt_v);
  __syncthreads();   // all waves done reading LN tile from A
#pragma unroll
  for (int rb = 0; rb < 4; ++rb)
#pragma unroll
    for (int r = 0; r < 4; ++r) {
      int row = rb * 16 + g * 4 + r;
#pragma unroll
      for (int cb = 0; cb < 4; ++cb)
        A[row * 256 + cols[cb]] = f2bf(acc[rb][cb][r] + vbias[cb]);   // plain layout
    }
  __syncthreads();
#pragma unroll
  for (int i = 0; i < 2; ++i) {
    int hr = i * 256 + tid;
    int row = hr >> 3, h = hr & 7;
    const s16x8* src = (const s16x8*)&A[row * 256 + h * 32];
    s16x8 v0 = src[0], v1 = src[1], v2 = src[2], v3 = src[3];
    s16x8* dst = (s16x8*)&vws[((size_t)(b * 8 + h) * 4096 + n0 + row) * 32];
    dst[0] = v0; dst[1] = v1; dst[2] = v2; dst[3] = v3;
  }
#undef DO_GEMM
}

// ---------------- attention: stats -> tanh rescale -> softmax -> weighted V ----------------
__global__ __launch_bounds__(256) void attn_kernel(
    const float* __restrict__ scores,
    const unsigned short* __restrict__ vws,
    float* __restrict__ out_attn) {
  int b = blockIdx.x >> 3, h = blockIdx.x & 7;
  const float* s0p = scores + (size_t)((b * 8 + h) * 2 + 0) * 4096;
  const float* s1p = scores + (size_t)((b * 8 + h) * 2 + 1) * 4096;
  float sa[16], sb[16];
  float a1 = 0.f, a2 = 0.f, b1 = 0.f, b2 = 0.f;
#pragma unroll
  for (int i = 0; i < 16; ++i) {
    int k = i * 256 + TID;
    sa[i] = s0p[k]; sb[i] = s1p[k];
    a1 += sa[i]; a2 += sa[i] * sa[i];
    b1 += sb[i]; b2 += sb[i] * sb[i];
  }
  __shared__ float red[16];
  int w = TID >> 6;
#pragma unroll
  for (int m = 1; m < 64; m <<= 1) {
    a1 += __shfl_xor(a1, m, 64); a2 += __shfl_xor(a2, m, 64);
    b1 += __shfl_xor(b1, m, 64); b2 += __shfl_xor(b2, m, 64);
  }
  if ((TID & 63) == 0) { red[w * 4] = a1; red[w * 4 + 1] = a2; red[w * 4 + 2] = b1; red[w * 4 + 3] = b2; }
  __syncthreads();
  a1 = red[0] + red[4] + red[8] + red[12];
  a2 = red[1] + red[5] + red[9] + red[13];
  b1 = red[2] + red[6] + red[10] + red[14];
  b2 = red[3] + red[7] + red[11] + red[15];
  float va = (a2 - a1 * a1 * (1.f / 4096.f)) * (1.f / 4095.f);   // ddof=1
  float vb = (b2 - b1 * b1 * (1.f / 4096.f)) * (1.f / 4095.f);
  float sga = fmaxf(sqrtf(fmaxf(va, 0.f)), 1e-3f);
  float sgb = fmaxf(sqrtf(fmaxf(vb, 0.f)), 1e-3f);
  float ia = 0.5f / sga, ib = 0.5f / sgb;
  float fa = 5.f * sga, fb = 5.f * sgb;
  float ea = 0.f, eb = 0.f;
#pragma unroll
  for (int i = 0; i < 16; ++i) {
    sa[i] = __expf(tanhf(sa[i] * ia) * fa);    // |arg| <= 5*sigma <= 0.89: no max-sub needed
    sb[i] = __expf(tanhf(sb[i] * ib) * fb);
    ea += sa[i]; eb += sb[i];
  }
#pragma unroll
  for (int m = 1; m < 64; m <<= 1) { ea += __shfl_xor(ea, m, 64); eb += __shfl_xor(eb, m, 64); }
  __syncthreads();  // red reuse: previous reads done
  if ((TID & 63) == 0) { red[w * 2] = ea; red[w * 2 + 1] = eb; }
  __syncthreads();
  ea = red[0] + red[2] + red[4] + red[6];
  eb = red[1] + red[3] + red[5] + red[7];
  float iea = 1.f / ea, ieb = 1.f / eb;   // (w + 1e-4) / (1 + 1e-8): denom == 1.0f in fp32
  float oa[32], ob[32];
#pragma unroll
  for (int d = 0; d < 32; ++d) { oa[d] = 0.f; ob[d] = 0.f; }
  const unsigned short* vbase = vws + (size_t)(b * 8 + h) * 4096 * 32;
#pragma unroll 4
  for (int i = 0; i < 16; ++i) {
    int k = i * 256 + TID;
    float wa = fmaf(sa[i], iea, 1e-4f);
    float wb = fmaf(sb[i], ieb, 1e-4f);
    const s16x8* vp = (const s16x8*)(vbase + (size_t)k * 32);
#pragma unroll
    for (int j = 0; j < 4; ++j) {
      s16x8 vv = vp[j];
#pragma unroll
      for (int t = 0; t < 8; ++t) {
        float vf = bf2f((unsigned short)vv[t]);
        oa[j * 8 + t] = fmaf(wa, vf, oa[j * 8 + t]);
        ob[j * 8 + t] = fmaf(wb, vf, ob[j * 8 + t]);
      }
    }
  }
#pragma unroll
  for (int m = 1; m < 64; m <<= 1) {
#pragma unroll
    for (int d = 0; d < 32; ++d) { oa[d] += __shfl_xor(oa[d], m, 64); ob[d] += __shfl_xor(ob[d], m, 64); }
  }
  __shared__ float R[4][64];
  if ((TID & 63) == 0) {
#pragma unroll
    for (int d = 0; d < 32; ++d) { R[w][d] = oa[d]; R[w][32 + d] = ob[d]; }
  }
  __syncthreads();
  if (TID < 64) {
    float s = R[0][TID] + R[1][TID] + R[2][TID] + R[3][TID];
    int q = TID >> 5, d = TID & 31;
    out_attn[(b * 2 + q) * 256 + h * 32 + d] = s;
  }
}

// ---------------- final: pooled + logits ----------------
__global__ __launch_bounds__(256) void final_kernel(
    const float* __restrict__ attn, const float* __restrict__ fc_w,
    const float* __restrict__ fc_b, float* __restrict__ out_pooled,
    float* __restrict__ out_logits) {
  int b = blockIdx.x;
  __shared__ float P[256];
  float p = 0.5f * (attn[(b * 2) * 256 + TID] + attn[(b * 2 + 1) * 256 + TID]);
  out_pooled[b * 256 + TID] = p;
  P[TID] = p;
  __syncthreads();
  if (TID < 40) {
    float acc = fc_b[TID];
#pragma unroll 8
    for (int i = 0; i < 256; ++i) acc = fmaf(P[i], fc_w[i * 40 + TID], acc);
    out_logits[b * 40 + TID] = acc;
  }
}

extern "C" void kernel_launch(void* const* d_in, const int* in_sizes, int n_in,
                              void* d_out, int out_size, void* d_ws, size_t ws_size,
                              hipStream_t stream) {
  (void)in_sizes; (void)n_in; (void)out_size; (void)ws_size;
  const float* eeg_feat  = (const float*)d_in[0];
  const float* stim_feat = (const float*)d_in[1];
  const float* temp_feat = (const float*)d_in[2];
  const float* eeg_w = (const float*)d_in[3];
  const float* eeg_b = (const float*)d_in[4];
  const float* stim_w = (const float*)d_in[5];
  const float* stim_b = (const float*)d_in[6];
  const float* temp_w = (const float*)d_in[7];
  const float* temp_b = (const float*)d_in[8];
  const float* q_w = (const float*)d_in[9];
  const float* q_b = (const float*)d_in[10];
  const float* k_w = (const float*)d_in[11];
  const float* k_b = (const float*)d_in[12];
  const float* v_w = (const float*)d_in[13];
  const float* v_b = (const float*)d_in[14];
  const float* fc_w = (const float*)d_in[15];
  const float* fc_b = (const float*)d_in[16];
  const float* lnq_g = (const float*)d_in[17];
  const float* lnq_b = (const float*)d_in[18];
  const float* lnk_g = (const float*)d_in[19];
  const float* lnk_b = (const float*)d_in[20];

  char* ws = (char*)d_ws;
  unsigned short* wt  = (unsigned short*)(ws + 0);        // 3 * 131072 B
  float2* trig        = (float2*)(ws + 393216);           // 512 KB
  float* qhat         = (float*)(ws + 917504);            // 64 KB
  float* scores       = (float*)(ws + 1048576);           // 8 MB
  unsigned short* vws = (unsigned short*)(ws + 9437184);  // 64 MB

  float* out = (float*)d_out;
  float* out_logits = out;                 // 32*40
  float* out_pooled = out + 1280;          // 32*256
  float* out_attn   = out + 9472;          // 32*2*256
  float* out_query  = out + 25856;         // 32*2*256

  prep_kernel<<<1024, 256, 0, stream>>>(eeg_w, k_w, v_w, wt, trig);
  q_kernel<<<64, 256, 0, stream>>>(stim_feat, temp_feat, stim_w, stim_b,
                                   temp_w, temp_b, q_w, q_b, lnq_g, lnq_b,
                                   out_query, qhat);
  main_kernel<<<2048, 256, 0, stream>>>(eeg_feat, eeg_b, k_b, v_b, lnk_g, lnk_b,
                                        wt, wt + 65536, wt + 131072,
                                        trig, qhat, scores, vws);
  attn_kernel<<<256, 256, 0, stream>>>(scores, vws, out_attn);
  final_kernel<<<32, 256, 0, stream>>>(out_attn, fc_w, fc_b, out_pooled, out_logits);
}

// Round 2
// 255.514 us; speedup vs baseline: 1.1580x; 1.1580x over previous
//
#include <hip/hip_runtime.h>
#include <hip/hip_bf16.h>
#include <math.h>

#define TID ((int)threadIdx.x)

typedef float f32x4 __attribute__((ext_vector_type(4)));
typedef short s16x8 __attribute__((ext_vector_type(8)));

__device__ __forceinline__ unsigned short f2bf(float f) {
  union { float f; unsigned u; } v; v.f = f;
  unsigned r = v.u + 0x7FFFu + ((v.u >> 16) & 1u);
  return (unsigned short)(r >> 16);
}
__device__ __forceinline__ float bf2f(unsigned short h) {
  union { unsigned u; float f; } v; v.u = ((unsigned)h) << 16;
  return v.f;
}

// ---------------- prep: weight transpose->bf16 + RoPE trig table ----------------
__global__ void prep_kernel(const float* __restrict__ eeg_w,
                            const float* __restrict__ k_w,
                            const float* __restrict__ v_w,
                            unsigned short* __restrict__ wt,
                            float2* __restrict__ trig) {
  int gid = blockIdx.x * 256 + TID;            // grid = 1024*256 = 262144 exactly
  if (gid < 3 * 65536) {
    int m = gid >> 16, e = gid & 65535;
    int i = e >> 8, j = e & 255;               // read W[i][j] coalesced over j
    const float* W = (m == 0) ? eeg_w : ((m == 1) ? k_w : v_w);
    wt[m * 65536 + j * 256 + i] = f2bf(W[i * 256 + j]);
  } else {
    int e = gid - 3 * 65536;                   // < 65536
    int n = e >> 4, p = e & 15;
    float inv = exp2f(-(float)p * 0.8304820237218406f);  // 10000^(-p/16)
    float a = (float)n * inv;
    trig[e] = make_float2(cosf(a), sinf(a));
  }
}

// ---------------- query path: proj -> LN (output) -> Q proj -> RoPE -> l2norm ----------------
__global__ __launch_bounds__(256) void q_kernel(
    const float* __restrict__ stim_feat, const float* __restrict__ temp_feat,
    const float* __restrict__ stim_w, const float* __restrict__ stim_b,
    const float* __restrict__ temp_w, const float* __restrict__ temp_b,
    const float* __restrict__ q_w, const float* __restrict__ q_b,
    const float* __restrict__ lnq_g, const float* __restrict__ lnq_b,
    float* __restrict__ out_query, float* __restrict__ qhat) {
  int b = blockIdx.x >> 1, q = blockIdx.x & 1;
  __shared__ float f[256];
  __shared__ float red[8];
  const float* feat = (q ? temp_feat : stim_feat) + b * 256;
  const float* W = q ? temp_w : stim_w;
  const float* bias = q ? temp_b : stim_b;
  f[TID] = feat[TID];
  __syncthreads();
  float acc = bias[TID];
#pragma unroll 8
  for (int i = 0; i < 256; ++i) acc = fmaf(f[i], W[i * 256 + TID], acc);
  float s1 = acc, s2 = acc * acc;
#pragma unroll
  for (int m = 1; m < 64; m <<= 1) { s1 += __shfl_xor(s1, m, 64); s2 += __shfl_xor(s2, m, 64); }
  if ((TID & 63) == 0) { red[TID >> 6] = s1; red[4 + (TID >> 6)] = s2; }
  __syncthreads();
  s1 = red[0] + red[1] + red[2] + red[3];
  s2 = red[4] + red[5] + red[6] + red[7];
  float mean = s1 * (1.f / 256.f);
  float var = s2 * (1.f / 256.f) - mean * mean;
  float rstd = rsqrtf(var + 1e-5f);
  float qln = (acc - mean) * rstd * lnq_g[TID] + lnq_b[TID];
  out_query[(b * 2 + q) * 256 + TID] = qln;
  __syncthreads();
  f[TID] = qln;
  __syncthreads();
  float a2 = q_b[TID];
#pragma unroll 8
  for (int i = 0; i < 256; ++i) a2 = fmaf(f[i], q_w[i * 256 + TID], a2);
  __syncthreads();
  f[TID] = a2;
  __syncthreads();
  float partner = f[TID ^ 1];
  int p = (TID >> 1) & 15;
  float inv = exp2f(-(float)p * 0.8304820237218406f);
  float ang = (float)q * inv;
  float cc_ = cosf(ang), ss_ = sinf(ang);
  float r = (TID & 1) ? fmaf(a2, cc_, partner * ss_) : fmaf(a2, cc_, -partner * ss_);
  float sq = r * r;
#pragma unroll
  for (int m = 1; m < 32; m <<= 1) sq += __shfl_xor(sq, m, 32);   // per-head (32 lanes)
  float rs = 1.f / fmaxf(sqrtf(sq), 1e-12f);
  qhat[(b * 2 + q) * 256 + TID] = r * rs;
}

// ---------------- main: eeg proj -> LN -> K proj (rot -> LDS) -> V proj ----------------
//                  -> data-parallel score phase (no cross-lane reductions)
__global__ __launch_bounds__(256) void main_kernel(
    const float* __restrict__ x,
    const float* __restrict__ eeg_b,
    const float* __restrict__ k_b,
    const float* __restrict__ v_b,
    const float* __restrict__ lnk_g,
    const float* __restrict__ lnk_b,
    const unsigned short* __restrict__ wt_eeg,
    const unsigned short* __restrict__ wt_k,
    const unsigned short* __restrict__ wt_v,
    const float2* __restrict__ trig,
    const float* __restrict__ qhat,
    float* __restrict__ scores,
    unsigned short* __restrict__ vws) {

  __shared__ __align__(16) unsigned short A[64 * 256];   // 32KB: X/LN tile (swizzled), then V (plain)
  __shared__ __align__(16) unsigned short K2[64 * 256];  // 32KB: RoPE'd K tile (swizzled); first 2KB alias PS
  __shared__ __align__(16) float TRQH[2048];             // 8KB: trig rows, later Q-hat
  __shared__ float2 ST[64];                              // (mean, rstd) per row

  float* PS = (float*)K2;          // LN partials [row][wave*2+{s,ss}] (time-disjoint with K2 use)
  float2* TR = (float2*)TRQH;      // trig rows (phase 0-2), then TRQH[0..511] = qhat (phase 3)

  const int tid = TID;
  const int w = tid >> 6, l = tid & 63, g = l >> 4, c = l & 15;
  const int r0 = blockIdx.x * 64;
  const int b = r0 >> 12;
  const int n0 = r0 & 4095;

  // ---- stage X (fp32 -> bf16, swizzled) + trig rows ----
#pragma unroll
  for (int i = 0; i < 8; ++i) {
    int ch = i * 256 + tid;
    int row = ch >> 5, cc = ch & 31;
    const float4* gp = (const float4*)(x + (size_t)(r0 + row) * 256 + cc * 8);
    float4 u0 = gp[0], u1 = gp[1];
    s16x8 pk;
    pk[0] = (short)f2bf(u0.x); pk[1] = (short)f2bf(u0.y);
    pk[2] = (short)f2bf(u0.z); pk[3] = (short)f2bf(u0.w);
    pk[4] = (short)f2bf(u1.x); pk[5] = (short)f2bf(u1.y);
    pk[6] = (short)f2bf(u1.z); pk[7] = (short)f2bf(u1.w);
    *(s16x8*)&A[row * 256 + ((cc ^ (row & 7)) * 8)] = pk;
  }
#pragma unroll
  for (int i = 0; i < 4; ++i) {
    int e = i * 256 + tid;  // < 1024
    int rr = e >> 4, pp = e & 15;
    TR[e] = trig[(size_t)(n0 + rr) * 16 + pp];
  }
  __syncthreads();

  f32x4 acc[4][4];

#define DO_GEMM(WT) do {                                                          \
    _Pragma("unroll") for (int rb = 0; rb < 4; ++rb)                              \
      _Pragma("unroll") for (int cb = 0; cb < 4; ++cb)                            \
        acc[rb][cb] = (f32x4){0.f, 0.f, 0.f, 0.f};                                \
    _Pragma("unroll") for (int ks = 0; ks < 8; ++ks) {                            \
      s16x8 af[4]; s16x8 bfr[4];                                                  \
      _Pragma("unroll") for (int rb = 0; rb < 4; ++rb) {                          \
        int row = rb * 16 + c; int kc = ks * 4 + g;                               \
        af[rb] = *(const s16x8*)&A[row * 256 + ((kc ^ (row & 7)) * 8)];           \
      }                                                                           \
      _Pragma("unroll") for (int cb = 0; cb < 4; ++cb) {                          \
        int col = w * 64 + cb * 16 + c;                                           \
        bfr[cb] = *(const s16x8*)&(WT)[col * 256 + ks * 32 + g * 8];              \
      }                                                                           \
      _Pragma("unroll") for (int rb = 0; rb < 4; ++rb)                            \
        _Pragma("unroll") for (int cb = 0; cb < 4; ++cb)                          \
          acc[rb][cb] = __builtin_amdgcn_mfma_f32_16x16x32_bf16(                  \
              af[rb], bfr[cb], acc[rb][cb], 0, 0, 0);                             \
    } } while (0)

  // per-lane column constants
  float ebias[4], kbias[4], vbias[4], gg[4], bb[4];
  int cols[4];
#pragma unroll
  for (int cb = 0; cb < 4; ++cb) {
    int col = w * 64 + cb * 16 + c;
    cols[cb] = col;
    ebias[cb] = eeg_b[col]; kbias[cb] = k_b[col]; vbias[cb] = v_b[col];
    gg[cb] = lnk_g[col]; bb[cb] = lnk_b[col];
  }

  // ---- GEMM1: eeg projection ----
  DO_GEMM(wt_eeg);

  // ---- LN stats from accumulators (wave shfl-reduce + cross-wave LDS) ----
  {
    float ps[4][4], pq[4][4];
#pragma unroll
    for (int rb = 0; rb < 4; ++rb)
#pragma unroll
      for (int r = 0; r < 4; ++r) {
        float s = 0.f, q2 = 0.f;
#pragma unroll
        for (int cb = 0; cb < 4; ++cb) {
          float v = acc[rb][cb][r] + ebias[cb];
          s += v; q2 += v * v;
        }
        ps[rb][r] = s; pq[rb][r] = q2;
      }
#pragma unroll
    for (int m = 1; m < 16; m <<= 1)
#pragma unroll
      for (int rb = 0; rb < 4; ++rb)
#pragma unroll
        for (int r = 0; r < 4; ++r) {
          ps[rb][r] += __shfl_xor(ps[rb][r], m, 64);
          pq[rb][r] += __shfl_xor(pq[rb][r], m, 64);
        }
    float outS = 0.f, outQ = 0.f;
#pragma unroll
    for (int rb = 0; rb < 4; ++rb)
#pragma unroll
      for (int r = 0; r < 4; ++r)
        if (c == rb * 4 + r) { outS = ps[rb][r]; outQ = pq[rb][r]; }
    int row = (c >> 2) * 16 + g * 4 + (c & 3);
    PS[row * 8 + w * 2 + 0] = outS;
    PS[row * 8 + w * 2 + 1] = outQ;
  }
  __syncthreads();
  if (tid < 64) {
    float s = PS[tid * 8 + 0] + PS[tid * 8 + 2] + PS[tid * 8 + 4] + PS[tid * 8 + 6];
    float q2 = PS[tid * 8 + 1] + PS[tid * 8 + 3] + PS[tid * 8 + 5] + PS[tid * 8 + 7];
    float mean = s * (1.f / 256.f);
    float var = q2 * (1.f / 256.f) - mean * mean;
    ST[tid] = make_float2(mean, rsqrtf(var + 1e-5f));
  }
  __syncthreads();

  // ---- LN -> bf16 back into A (all GEMM1 A-reads completed; PS reads done) ----
#pragma unroll
  for (int rb = 0; rb < 4; ++rb)
#pragma unroll
    for (int r = 0; r < 4; ++r) {
      int row = rb * 16 + g * 4 + r;
      float2 st = ST[row];
#pragma unroll
      for (int cb = 0; cb < 4; ++cb) {
        float v = (acc[rb][cb][r] + ebias[cb] - st.x) * st.y * gg[cb] + bb[cb];
        A[row * 256 + (cols[cb] ^ ((row & 7) * 8))] = f2bf(v);
      }
    }
  __syncthreads();

  // ---- GEMM2: K projection; epilogue: bias + RoPE -> K2 (swizzled bf16) ----
  DO_GEMM(wt_k);
#pragma unroll
  for (int rb = 0; rb < 4; ++rb)
#pragma unroll
    for (int cb = 0; cb < 4; ++cb) {
      int pp = (cols[cb] >> 1) & 15;
#pragma unroll
      for (int r = 0; r < 4; ++r) {
        int row = rb * 16 + g * 4 + r;
        float v = acc[rb][cb][r] + kbias[cb];
        float pv = __shfl_xor(v, 1, 64);           // partner column (col^1)
        float2 cs2 = TR[row * 16 + pp];
        float rv = (c & 1) ? fmaf(v, cs2.x, pv * cs2.y)
                           : fmaf(v, cs2.x, -pv * cs2.y);
        K2[row * 256 + (cols[cb] ^ ((row & 7) * 8))] = f2bf(rv);
      }
    }

  // ---- GEMM3: V projection (A still holds LN tile) ----
  DO_GEMM(wt_v);
  __syncthreads();   // A-reads done by all waves; K2 writes visible

  // ---- V -> A (plain layout) + stage qhat into TRQH (TR reads all done) ----
#pragma unroll
  for (int rb = 0; rb < 4; ++rb)
#pragma unroll
    for (int r = 0; r < 4; ++r) {
      int row = rb * 16 + g * 4 + r;
#pragma unroll
      for (int cb = 0; cb < 4; ++cb)
        A[row * 256 + cols[cb]] = f2bf(acc[rb][cb][r] + vbias[cb]);
    }
  TRQH[tid] = qhat[(size_t)b * 512 + tid];
  TRQH[256 + tid] = qhat[(size_t)b * 512 + 256 + tid];
  __syncthreads();

  // ---- coalesced V write to vws[b][h][n][32] ----
#pragma unroll
  for (int i = 0; i < 2; ++i) {
    int hr = i * 256 + tid;
    int row = hr >> 3, hh = hr & 7;
    const s16x8* src = (const s16x8*)&A[row * 256 + hh * 32];
    s16x8 v0 = src[0], v1 = src[1], v2 = src[2], v3 = src[3];
    s16x8* dst = (s16x8*)&vws[((size_t)(b * 8 + hh) * 4096 + n0 + row) * 32];
    dst[0] = v0; dst[1] = v1; dst[2] = v2; dst[3] = v3;
  }

  // ---- data-parallel score phase: 512 cells = 64 rows x 8 heads, 2 per thread ----
  // wave w handles head w (cell0) and head 4+w (cell1); lane l -> row l.
  // Per cell: ssq + dot(Q0) + dot(Q1) over 32 cols, all in-thread (no shuffles).
#pragma unroll
  for (int cell = 0; cell < 2; ++cell) {
    int h = cell * 4 + w;
    int row = l;
    float ssq = 0.f, d0 = 0.f, d1 = 0.f;
#pragma unroll
    for (int j = 0; j < 4; ++j) {
      s16x8 kv = *(const s16x8*)&K2[row * 256 + (((h * 4 + j) ^ (row & 7)) * 8)];
#pragma unroll
      for (int t = 0; t < 8; ++t) {
        float kf = bf2f((unsigned short)kv[t]);
        int col = h * 32 + j * 8 + t;
        ssq = fmaf(kf, kf, ssq);
        d0 = fmaf(kf, TRQH[col], d0);
        d1 = fmaf(kf, TRQH[256 + col], d1);
      }
    }
    float is = 0.17677669529663687f / fmaxf(sqrtf(ssq), 1e-12f);
    scores[(size_t)((b * 8 + h) * 2 + 0) * 4096 + n0 + row] = d0 * is;
    scores[(size_t)((b * 8 + h) * 2 + 1) * 4096 + n0 + row] = d1 * is;
  }
#undef DO_GEMM
}

// ---------------- attention: stats -> tanh rescale -> softmax -> weighted V ----------------
__global__ __launch_bounds__(256) void attn_kernel(
    const float* __restrict__ scores,
    const unsigned short* __restrict__ vws,
    float* __restrict__ out_attn) {
  int b = blockIdx.x >> 3, h = blockIdx.x & 7;
  const float* s0p = scores + (size_t)((b * 8 + h) * 2 + 0) * 4096;
  const float* s1p = scores + (size_t)((b * 8 + h) * 2 + 1) * 4096;
  float sa[16], sb[16];
  float a1 = 0.f, a2 = 0.f, b1 = 0.f, b2 = 0.f;
#pragma unroll
  for (int i = 0; i < 16; ++i) {
    int k = i * 256 + TID;
    sa[i] = s0p[k]; sb[i] = s1p[k];
    a1 += sa[i]; a2 += sa[i] * sa[i];
    b1 += sb[i]; b2 += sb[i] * sb[i];
  }
  __shared__ float red[16];
  int w = TID >> 6;
#pragma unroll
  for (int m = 1; m < 64; m <<= 1) {
    a1 += __shfl_xor(a1, m, 64); a2 += __shfl_xor(a2, m, 64);
    b1 += __shfl_xor(b1, m, 64); b2 += __shfl_xor(b2, m, 64);
  }
  if ((TID & 63) == 0) { red[w * 4] = a1; red[w * 4 + 1] = a2; red[w * 4 + 2] = b1; red[w * 4 + 3] = b2; }
  __syncthreads();
  a1 = red[0] + red[4] + red[8] + red[12];
  a2 = red[1] + red[5] + red[9] + red[13];
  b1 = red[2] + red[6] + red[10] + red[14];
  b2 = red[3] + red[7] + red[11] + red[15];
  float va = (a2 - a1 * a1 * (1.f / 4096.f)) * (1.f / 4095.f);   // ddof=1
  float vb = (b2 - b1 * b1 * (1.f / 4096.f)) * (1.f / 4095.f);
  float sga = fmaxf(sqrtf(fmaxf(va, 0.f)), 1e-3f);
  float sgb = fmaxf(sqrtf(fmaxf(vb, 0.f)), 1e-3f);
  float ia = 0.5f / sga, ib = 0.5f / sgb;
  float fa = 5.f * sga, fb = 5.f * sgb;
  float ea = 0.f, eb = 0.f;
#pragma unroll
  for (int i = 0; i < 16; ++i) {
    sa[i] = __expf(tanhf(sa[i] * ia) * fa);    // |arg| <= 5*sigma <= 0.89: no max-sub needed
    sb[i] = __expf(tanhf(sb[i] * ib) * fb);
    ea += sa[i]; eb += sb[i];
  }
#pragma unroll
  for (int m = 1; m < 64; m <<= 1) { ea += __shfl_xor(ea, m, 64); eb += __shfl_xor(eb, m, 64); }
  __syncthreads();  // red reuse: previous reads done
  if ((TID & 63) == 0) { red[w * 2] = ea; red[w * 2 + 1] = eb; }
  __syncthreads();
  ea = red[0] + red[2] + red[4] + red[6];
  eb = red[1] + red[3] + red[5] + red[7];
  float iea = 1.f / ea, ieb = 1.f / eb;   // (w + 1e-4) / (1 + 1e-8): denom == 1.0f in fp32
  float oa[32], ob[32];
#pragma unroll
  for (int d = 0; d < 32; ++d) { oa[d] = 0.f; ob[d] = 0.f; }
  const unsigned short* vbase = vws + (size_t)(b * 8 + h) * 4096 * 32;
#pragma unroll 4
  for (int i = 0; i < 16; ++i) {
    int k = i * 256 + TID;
    float wa = fmaf(sa[i], iea, 1e-4f);
    float wb = fmaf(sb[i], ieb, 1e-4f);
    const s16x8* vp = (const s16x8*)(vbase + (size_t)k * 32);
#pragma unroll
    for (int j = 0; j < 4; ++j) {
      s16x8 vv = vp[j];
#pragma unroll
      for (int t = 0; t < 8; ++t) {
        float vf = bf2f((unsigned short)vv[t]);
        oa[j * 8 + t] = fmaf(wa, vf, oa[j * 8 + t]);
        ob[j * 8 + t] = fmaf(wb, vf, ob[j * 8 + t]);
      }
    }
  }
#pragma unroll
  for (int m = 1; m < 64; m <<= 1) {
#pragma unroll
    for (int d = 0; d < 32; ++d) { oa[d] += __shfl_xor(oa[d], m, 64); ob[d] += __shfl_xor(ob[d], m, 64); }
  }
  __shared__ float R[4][64];
  if ((TID & 63) == 0) {
#pragma unroll
    for (int d = 0; d < 32; ++d) { R[w][d] = oa[d]; R[w][32 + d] = ob[d]; }
  }
  __syncthreads();
  if (TID < 64) {
    float s = R[0][TID] + R[1][TID] + R[2][TID] + R[3][TID];
    int q = TID >> 5, d = TID & 31;
    out_attn[(b * 2 + q) * 256 + h * 32 + d] = s;
  }
}

// ---------------- final: pooled + logits ----------------
__global__ __launch_bounds__(256) void final_kernel(
    const float* __restrict__ attn, const float* __restrict__ fc_w,
    const float* __restrict__ fc_b, float* __restrict__ out_pooled,
    float* __restrict__ out_logits) {
  int b = blockIdx.x;
  __shared__ float P[256];
  float p = 0.5f * (attn[(b * 2) * 256 + TID] + attn[(b * 2 + 1) * 256 + TID]);
  out_pooled[b * 256 + TID] = p;
  P[TID] = p;
  __syncthreads();
  if (TID < 40) {
    float acc = fc_b[TID];
#pragma unroll 8
    for (int i = 0; i < 256; ++i) acc = fmaf(P[i], fc_w[i * 40 + TID], acc);
    out_logits[b * 40 + TID] = acc;
  }
}

extern "C" void kernel_launch(void* const* d_in, const int* in_sizes, int n_in,
                              void* d_out, int out_size, void* d_ws, size_t ws_size,
                              hipStream_t stream) {
  (void)in_sizes; (void)n_in; (void)out_size; (void)ws_size;
  const float* eeg_feat  = (const float*)d_in[0];
  const float* stim_feat = (const float*)d_in[1];
  const float* temp_feat = (const float*)d_in[2];
  const float* eeg_w = (const float*)d_in[3];
  const float* eeg_b = (const float*)d_in[4];
  const float* stim_w = (const float*)d_in[5];
  const float* stim_b = (const float*)d_in[6];
  const float* temp_w = (const float*)d_in[7];
  const float* temp_b = (const float*)d_in[8];
  const float* q_w = (const float*)d_in[9];
  const float* q_b = (const float*)d_in[10];
  const float* k_w = (const float*)d_in[11];
  const float* k_b = (const float*)d_in[12];
  const float* v_w = (const float*)d_in[13];
  const float* v_b = (const float*)d_in[14];
  const float* fc_w = (const float*)d_in[15];
  const float* fc_b = (const float*)d_in[16];
  const float* lnq_g = (const float*)d_in[17];
  const float* lnq_b = (const float*)d_in[18];
  const float* lnk_g = (const float*)d_in[19];
  const float* lnk_b = (const float*)d_in[20];

  char* ws = (char*)d_ws;
  unsigned short* wt  = (unsigned short*)(ws + 0);        // 3 * 131072 B
  float2* trig        = (float2*)(ws + 393216);           // 512 KB
  float* qhat         = (float*)(ws + 917504);            // 64 KB
  float* scores       = (float*)(ws + 1048576);           // 8 MB
  unsigned short* vws = (unsigned short*)(ws + 9437184);  // 64 MB

  float* out = (float*)d_out;
  float* out_logits = out;                 // 32*40
  float* out_pooled = out + 1280;          // 32*256
  float* out_attn   = out + 9472;          // 32*2*256
  float* out_query  = out + 25856;         // 32*2*256

  prep_kernel<<<1024, 256, 0, stream>>>(eeg_w, k_w, v_w, wt, trig);
  q_kernel<<<64, 256, 0, stream>>>(stim_feat, temp_feat, stim_w, stim_b,
                                   temp_w, temp_b, q_w, q_b, lnq_g, lnq_b,
                                   out_query, qhat);
  main_kernel<<<2048, 256, 0, stream>>>(eeg_feat, eeg_b, k_b, v_b, lnk_g, lnk_b,
                                        wt, wt + 65536, wt + 131072,
                                        trig, qhat, scores, vws);
  attn_kernel<<<256, 256, 0, stream>>>(scores, vws, out_attn);
  final_kernel<<<32, 256, 0, stream>>>(out_attn, fc_w, fc_b, out_pooled, out_logits);
}